// Round 7
// baseline (777.100 us; speedup 1.0000x reference)
//
#include <hip/hip_runtime.h>

#define N_NODES 100000
#define N_EDGES 1600000
#define EMBED_DIM 64

#define RPB 128                                    // rows per bucket
#define NBKT ((N_NODES + RPB - 1) / RPB)           // 782
#define TILE 4096                                  // edges per binA tile
#define NTILE ((N_EDGES + TILE - 1) / TILE)        // 391
#define DIRW (NBKT + 1)                            // 783 (with per-tile sentinel)
#define ECAP 2432                                  // bucket mean 2046, +8.5 sigma

// ---------- pass 1: per-tile counting sort by bucket; LINEAR dense flush ----------
// No global atomics: tile t's edges land at packed[t*TILE ...], grouped by
// bucket; dir[t][b] = global start of (t,b) segment, dir[t][NBKT] = sentinel.
__global__ __launch_bounds__(512) void k_binA(const int* __restrict__ rows,
                                              const int* __restrict__ cols,
                                              const float* __restrict__ vals,
                                              int2* __restrict__ packed,
                                              int* __restrict__ dir) {
    __shared__ int hist[NBKT];
    __shared__ int cur[NBKT];
    __shared__ int ssum[512];
    __shared__ int2 stage[TILE];   // 32 KB
    const int tid = threadIdx.x;
    const int t = blockIdx.x;
    const int e0 = t * TILE;
    const int nt = min(TILE, N_EDGES - e0);

    for (int i = tid; i < NBKT; i += 512) hist[i] = 0;
    __syncthreads();

    for (int i = tid; i < nt; i += 512) atomicAdd(&hist[rows[e0 + i] >> 7], 1);
    __syncthreads();

    // exclusive scan over 782 buckets (2 per thread)
    int b0 = 2 * tid, b1 = 2 * tid + 1;
    int h0 = (b0 < NBKT) ? hist[b0] : 0;
    int h1 = (b1 < NBKT) ? hist[b1] : 0;
    ssum[tid] = h0 + h1;
    __syncthreads();
    for (int o = 1; o < 512; o <<= 1) {
        int a = ssum[tid];
        int add = (tid >= o) ? ssum[tid - o] : 0;
        __syncthreads();
        ssum[tid] = a + add;
        __syncthreads();
    }
    int base = (tid == 0) ? 0 : ssum[tid - 1];
    if (b0 < NBKT) { cur[b0] = base;      dir[t * DIRW + b0] = e0 + base; }
    if (b1 < NBKT) { cur[b1] = base + h0; dir[t * DIRW + b1] = e0 + base + h0; }
    if (tid == 0) dir[t * DIRW + NBKT] = e0 + nt;
    __syncthreads();

    // placement: group by bucket in LDS
    for (int i = tid; i < nt; i += 512) {
        int e = e0 + i;
        int r = rows[e];
        int p = atomicAdd(&cur[r >> 7], 1);
        stage[p] = make_int2(((r & (RPB - 1)) << 17) | cols[e],
                             __float_as_int(vals[e]));
    }
    __syncthreads();

    // linear flush: fully dense, coalesced
    for (int j = tid; j < nt; j += 512) packed[e0 + j] = stage[j];
}

// ---------- pass 2: one block per bucket; compact segments to LDS, accumulate ----------
__global__ __launch_bounds__(512) void k_accum(const float* __restrict__ x,
                                               const int* __restrict__ dir,
                                               const int2* __restrict__ packed,
                                               float* __restrict__ out) {
    __shared__ float acc[RPB * EMBED_DIM];  // 32 KB
    __shared__ int2 est[ECAP];              // 19 KB
    __shared__ int scnt[NTILE];
    __shared__ int soff[NTILE];
    __shared__ int sstart[NTILE];
    __shared__ int ssum[512];
    const int tid = threadIdx.x;
    const int b = blockIdx.x;

    for (int i = tid; i < RPB * EMBED_DIM / 4; i += 512)
        ((float4*)acc)[i] = make_float4(0.f, 0.f, 0.f, 0.f);

    // segment meta: adjacent-pair read per tile
    if (tid < NTILE) {
        int s = dir[tid * DIRW + b];
        int e = dir[tid * DIRW + b + 1];
        sstart[tid] = s;
        scnt[tid] = e - s;
    }
    __syncthreads();

    // block scan of segment counts
    int c = (tid < NTILE) ? scnt[tid] : 0;
    ssum[tid] = c;
    __syncthreads();
    for (int o = 1; o < 512; o <<= 1) {
        int a = ssum[tid];
        int add = (tid >= o) ? ssum[tid - o] : 0;
        __syncthreads();
        ssum[tid] = a + add;
        __syncthreads();
    }
    int total = ssum[511];
    if (tid < NTILE) soff[tid] = ssum[tid] - c;
    __syncthreads();

    // compact segments into LDS (thread t handles tile t's ~5 edges)
    if (tid < NTILE) {
        int s = sstart[tid], cc = scnt[tid], o = soff[tid];
        for (int k = 0; k < cc; ++k) {
            int2 ed = packed[s + k];
            int d = o + k;
            if (d < ECAP) {
                est[d] = ed;
            } else {  // statistically-never slow path (correct for any input)
                int col = ed.x & 0x1FFFF;
                int lr  = ((unsigned)ed.x) >> 17;
                float v = __int_as_float(ed.y);
                for (int q = 0; q < EMBED_DIM; ++q)
                    atomicAdd(&acc[lr * EMBED_DIM + q], v * x[col * EMBED_DIM + q]);
            }
        }
    }
    __syncthreads();

    int n = total;
    if (n > ECAP) n = ECAP;
    const int w = tid >> 6, lane = tid & 63;

    // main rounds: 8 waves x 8-deep unroll -> 8 gather loads in flight/wave
    int e8 = w * 8;
    for (; e8 + 8 <= n; e8 += 64) {
        int2 ed[8];
#pragma unroll
        for (int k = 0; k < 8; ++k) ed[k] = est[e8 + k];  // LDS broadcast
        float xv[8];
#pragma unroll
        for (int k = 0; k < 8; ++k)
            xv[k] = x[(ed[k].x & 0x1FFFF) * EMBED_DIM + lane];
#pragma unroll
        for (int k = 0; k < 8; ++k)
            atomicAdd(&acc[(((unsigned)ed[k].x) >> 17) * EMBED_DIM + lane],
                      __int_as_float(ed[k].y) * xv[k]);
    }
    // tail (<8 edges), wave 0 only
    if (w == 0) {
        for (int idx = n & ~7; idx < n; ++idx) {
            int2 ed = est[idx];
            atomicAdd(&acc[(((unsigned)ed.x) >> 17) * EMBED_DIM + lane],
                      __int_as_float(ed.y) * x[(ed.x & 0x1FFFF) * EMBED_DIM + lane]);
        }
    }
    __syncthreads();

    // dense output write: 128 rows x 64 dims as float4
    const int r0 = b * RPB;
    float4* o4 = (float4*)out;
    const float4* a4 = (const float4*)acc;
    for (int i = tid; i < RPB * EMBED_DIM / 4; i += 512) {
        int r = r0 + (i >> 4);
        if (r < N_NODES) o4[(size_t)r * 16 + (i & 15)] = a4[i];
    }
}

// ---------- fallback (ws too small): atomic scatter ----------
__global__ __launch_bounds__(256) void spmm_scatter_kernel(
    const float* __restrict__ x, const float* __restrict__ vals,
    const int* __restrict__ rows, const int* __restrict__ cols,
    float* __restrict__ out) {
    const int wave_in_block = threadIdx.x >> 6;
    const int lane = threadIdx.x & 63;
    const int e = blockIdx.x * 4 + wave_in_block;
    if (e >= N_EDGES) return;
    const float m = vals[e] * x[cols[e] * EMBED_DIM + lane];
    atomicAdd(&out[rows[e] * EMBED_DIM + lane], m);
}

extern "C" void kernel_launch(void* const* d_in, const int* in_sizes, int n_in,
                              void* d_out, int out_size, void* d_ws, size_t ws_size,
                              hipStream_t stream) {
    const float* x    = (const float*)d_in[0];
    const float* vals = (const float*)d_in[1];
    const int*   rows = (const int*)d_in[2];
    const int*   cols = (const int*)d_in[3];
    float* out = (float*)d_out;

    // ws: packed int2[NTILE*TILE] | dir int[NTILE*DIRW]
    const size_t packed_b = (size_t)NTILE * TILE * 8;   // 12,812,288
    const size_t dir_b    = (size_t)NTILE * DIRW * 4;   //  1,224,612
    const size_t need = packed_b + dir_b;               // ~14.04 MB

    if (ws_size < need) {
        hipMemsetAsync(out, 0, (size_t)out_size * sizeof(float), stream);
        spmm_scatter_kernel<<<(N_EDGES + 3) / 4, 256, 0, stream>>>(x, vals, rows, cols, out);
        return;
    }

    int2* packed = (int2*)d_ws;
    int*  dir    = (int*)((char*)d_ws + packed_b);

    k_binA<<<NTILE, 512, 0, stream>>>(rows, cols, vals, packed, dir);
    k_accum<<<NBKT, 512, 0, stream>>>(x, dir, packed, out);
}